// Round 5
// baseline (1570.878 us; speedup 1.0000x reference)
//
#include <hip/hip_runtime.h>
#include <math.h>

#define N_ATOMS 50000
#define D 32
#define E_EDGES 300000
#define BD 16
#define NCH 17              // BD + 1 bias channel
#define QW (NCH * D)        // 544
#define TILE 16
#define NTILES (N_ATOMS / TILE)               // 3125 exact
#define SCAN_BLOCKS ((N_ATOMS + 255) / 256)   // 196
#define GRU_TILE 8
#define GRU_NT (N_ATOMS / GRU_TILE)           // 6250

__device__ __forceinline__ float sigmoidf_(float x) {
    return 1.0f / (1.0f + __expf(-x));
}
__device__ __forceinline__ float dot4_(float4 a, float4 b, float acc) {
    return fmaf(a.x, b.x, fmaf(a.y, b.y, fmaf(a.z, b.z, fmaf(a.w, b.w, acc))));
}

// ---------- precompute kernels (once per launch) ----------

// WT2[i][s], i-major, s = b*32 + j ; channel b=16 is Bm (bias.reshape(D,D))
__global__ void k_build_wt(const float* __restrict__ kern,
                           const float* __restrict__ bias,
                           float* __restrict__ WT2) {
    int idx = blockIdx.x * 256 + threadIdx.x;
    if (idx >= D * QW) return;
    int i = idx / QW;
    int s = idx - i * QW;
    int b = s >> 5, j = s & 31;
    WT2[idx] = (b < BD) ? kern[b * (D * D) + i * D + j] : bias[i * D + j];
}

__global__ void k_hist(const int* __restrict__ pair, int* __restrict__ deg) {
    int e = blockIdx.x * 256 + threadIdx.x;
    if (e < E_EDGES) atomicAdd(&deg[pair[2 * e]], 1);
}

__global__ void k_scan1(const int* __restrict__ deg, int* __restrict__ offs,
                        int* __restrict__ bsums) {
    __shared__ int sm[256];
    int t = threadIdx.x, gid = blockIdx.x * 256 + t;
    int v = (gid < N_ATOMS) ? deg[gid] : 0;
    sm[t] = v;
    __syncthreads();
    for (int off = 1; off < 256; off <<= 1) {
        int x = (t >= off) ? sm[t - off] : 0;
        __syncthreads();
        sm[t] += x;
        __syncthreads();
    }
    if (gid < N_ATOMS) offs[gid] = sm[t] - v;
    if (t == 255) bsums[blockIdx.x] = sm[255];
}

__global__ void k_scan2(const int* __restrict__ bsums, int* __restrict__ boffs, int nb) {
    __shared__ int sm[256];
    int t = threadIdx.x;
    int v = (t < nb) ? bsums[t] : 0;
    sm[t] = v;
    __syncthreads();
    for (int off = 1; off < 256; off <<= 1) {
        int x = (t >= off) ? sm[t - off] : 0;
        __syncthreads();
        sm[t] += x;
        __syncthreads();
    }
    if (t < nb) boffs[t] = sm[t] - v;
}

__global__ void k_scan3(int* __restrict__ offs, const int* __restrict__ boffs) {
    int gid = blockIdx.x * 256 + threadIdx.x;
    if (gid < N_ATOMS) offs[gid] += boffs[blockIdx.x];
}

// sedge.x = src | (r_local << 20), sedge.y = eid   (src < 2^17, r_local < 16)
__global__ void k_scatter(const int* __restrict__ pair, const int* __restrict__ offs,
                          int* __restrict__ cursor, int2* __restrict__ sedge) {
    int e = blockIdx.x * 256 + threadIdx.x;
    if (e >= E_EDGES) return;
    int d = pair[2 * e], s = pair[2 * e + 1];
    int pos = offs[d] + atomicAdd(&cursor[d], 1);
    sedge[pos] = make_int2(s | ((d & (TILE - 1)) << 20), e);
}

// ---------- message kernel: phases 1+2, writes agg to global ----------
// __launch_bounds__(256,2): request 2 waves/EU min -> allows ~128+ VGPRs.
// r1 evidence: this config allocates 88 VGPR, zero scratch. Default/(256,4)
// pinned the allocator to the 64-VGPR step and spilled q[17] into the edge
// loop (225 MB/step scratch writes, r2-r4).
__global__ __launch_bounds__(256, 2)
void k_msg(const float* __restrict__ h_in, float* __restrict__ agg_g,
           const float* __restrict__ bond, const float* __restrict__ WT2,
           const int* __restrict__ offs, const int* __restrict__ deg,
           const int2* __restrict__ sedge) {
    __shared__ float q_lds[TILE][QW];     // 34816 B, bank(s) = s&31
    __shared__ float agg_lds[TILE][33];   // 2112 B

    const int t = threadIdx.x;
    const int base = blockIdx.x * TILE;
    const int half = t >> 5;   // 0..7
    const int j = t & 31;

    // ---- prologue: zero q_lds / agg_lds
#pragma unroll
    for (int k = 0; k < (TILE * QW) / 256; ++k)
        ((float*)q_lds)[t + 256 * k] = 0.f;
    {
        const int r = t >> 5;
        agg_lds[r][j]     = 0.f;
        agg_lds[r + 8][j] = 0.f;
    }
    __syncthreads();

    // ---- phase 1: edge-parallel q accumulation (8 half-wave chunks)
    {
        const int estart = offs[base];
        const int last = base + TILE - 1;
        const int eend = offs[last] + deg[last];
        const int cs = (eend - estart + 7) >> 3;
        int p = estart + half * cs;
        const int pe = min(p + cs, eend);

        float q[NCH];
#pragma unroll
        for (int k = 0; k < NCH; ++k) q[k] = 0.f;
        int rcur = -1;

        for (; p < pe; ++p) {
            const int2 ed = sedge[p];
            const int r = ed.x >> 20;
            const int src = ed.x & 0xFFFFF;
            if (r != rcur) {
                if (rcur >= 0) {
#pragma unroll
                    for (int k = 0; k < NCH; ++k) {
                        atomicAdd(&q_lds[rcur][k * 32 + j], q[k]);
                        q[k] = 0.f;
                    }
                }
                rcur = r;
            }
            const float hj = h_in[src * D + j];
            const float4* bp = (const float4*)(bond + (size_t)ed.y * BD);
            float4 b;
            b = bp[0];
            q[0] = fmaf(b.x, hj, q[0]);
            q[1] = fmaf(b.y, hj, q[1]);
            q[2] = fmaf(b.z, hj, q[2]);
            q[3] = fmaf(b.w, hj, q[3]);
            b = bp[1];
            q[4] = fmaf(b.x, hj, q[4]);
            q[5] = fmaf(b.y, hj, q[5]);
            q[6] = fmaf(b.z, hj, q[6]);
            q[7] = fmaf(b.w, hj, q[7]);
            b = bp[2];
            q[8]  = fmaf(b.x, hj, q[8]);
            q[9]  = fmaf(b.y, hj, q[9]);
            q[10] = fmaf(b.z, hj, q[10]);
            q[11] = fmaf(b.w, hj, q[11]);
            b = bp[3];
            q[12] = fmaf(b.x, hj, q[12]);
            q[13] = fmaf(b.y, hj, q[13]);
            q[14] = fmaf(b.z, hj, q[14]);
            q[15] = fmaf(b.w, hj, q[15]);
            q[16] += hj;
        }
        if (rcur >= 0) {
#pragma unroll
            for (int k = 0; k < NCH; ++k)
                atomicAdd(&q_lds[rcur][k * 32 + j], q[k]);
        }
    }
    __syncthreads();

    // ---- phase 2: agg[r][j] += sum_{s in my 68-chunk} WT2[j][s] * q[r][s]
    {
        const int s0 = half * (QW / 8);   // 68-wide, 16B-aligned (272 B)
        const float4* wrow = (const float4*)(WT2 + (size_t)j * QW + s0);
#pragma unroll
        for (int pass = 0; pass < 2; ++pass) {
            const int rb = ((pass ^ (half & 1)) & 1) * 8;
            float acc[8];
#pragma unroll
            for (int r = 0; r < 8; ++r) acc[r] = 0.f;
            for (int sq = 0; sq < (QW / 8) / 4; ++sq) {    // 17 iters
                const float4 wv = wrow[sq];
#pragma unroll
                for (int r = 0; r < 8; ++r) {
                    const float4 qv = *(const float4*)&q_lds[rb + r][s0 + sq * 4];
                    acc[r] = dot4_(wv, qv, acc[r]);
                }
            }
#pragma unroll
            for (int r = 0; r < 8; ++r)
                atomicAdd(&agg_lds[rb + r][j], acc[r]);
        }
    }
    __syncthreads();

    // ---- epilogue: agg -> global (coalesced)
    {
        const int r = t >> 5;
        agg_g[base * D + t]       = agg_lds[r][j];
        agg_g[base * D + 256 + t] = agg_lds[r + 8][j];
    }
}

// ---------- GRU kernel: h_out = GRUCell(agg, h_in) ----------
__global__ __launch_bounds__(256, 2)
void k_gru(const float* __restrict__ agg_g, const float* __restrict__ h_in,
           float* __restrict__ h_out,
           const float* __restrict__ Wih, const float* __restrict__ Whh,
           const float* __restrict__ bih, const float* __restrict__ bhh) {
    __shared__ float Wih_s[96][33];       // 12672 B
    __shared__ float Whh_s[96][33];       // 12672 B
    __shared__ float bih_s[96], bhh_s[96];
    __shared__ float x_lds[GRU_TILE][32];
    __shared__ float h_lds[GRU_TILE][32];

    const int t = threadIdx.x;

    for (int idx = t; idx < 96 * 32; idx += 256) {
        const int o = idx >> 5, j = idx & 31;
        Wih_s[o][j] = Wih[idx];
        Whh_s[o][j] = Whh[idx];
    }
    if (t < 96) { bih_s[t] = bih[t]; bhh_s[t] = bhh[t]; }
    __syncthreads();

    const int r = t >> 5;   // node within octet
    const int i = t & 31;   // output feature

    for (int tile = blockIdx.x; tile < GRU_NT; tile += gridDim.x) {
        const int base = tile * GRU_TILE;         // 8 nodes
        ((float*)x_lds)[t] = agg_g[base * D + t];
        ((float*)h_lds)[t] = h_in[base * D + t];
        __syncthreads();

        float gri = bih_s[i],      grh = bhh_s[i];
        float gzi = bih_s[32 + i], gzh = bhh_s[32 + i];
        float gni = bih_s[64 + i], gnh = bhh_s[64 + i];
#pragma unroll 8
        for (int jj = 0; jj < 32; ++jj) {
            const float xv = x_lds[r][jj];
            const float hv = h_lds[r][jj];
            gri = fmaf(Wih_s[i][jj],      xv, gri);
            gzi = fmaf(Wih_s[32 + i][jj], xv, gzi);
            gni = fmaf(Wih_s[64 + i][jj], xv, gni);
            grh = fmaf(Whh_s[i][jj],      hv, grh);
            gzh = fmaf(Whh_s[32 + i][jj], hv, gzh);
            gnh = fmaf(Whh_s[64 + i][jj], hv, gnh);
        }
        const float rg = sigmoidf_(gri + grh);
        const float zg = sigmoidf_(gzi + gzh);
        float xn = gni + rg * gnh;
        xn = fminf(fmaxf(xn, -15.f), 15.f);
        const float e2 = __expf(2.f * xn);
        const float ng = (e2 - 1.f) / (e2 + 1.f);
        h_out[base * D + t] = (1.f - zg) * ng + zg * h_lds[r][i];
        __syncthreads();
    }
}

// ---------- launch ----------
extern "C" void kernel_launch(void* const* d_in, const int* in_sizes, int n_in,
                              void* d_out, int out_size, void* d_ws, size_t ws_size,
                              hipStream_t stream) {
    const float* atom = (const float*)d_in[0];
    const float* bond = (const float*)d_in[1];
    const int*   pair = (const int*)d_in[2];
    const float* kern = (const float*)d_in[3];
    const float* bias = (const float*)d_in[4];
    const float* Wih  = (const float*)d_in[5];
    const float* Whh  = (const float*)d_in[6];
    const float* bih  = (const float*)d_in[7];
    const float* bhh  = (const float*)d_in[8];
    float* out = (float*)d_out;

    char* w = (char*)d_ws;
    auto alloc = [&](size_t bytes) {
        char* p = w;
        w += (bytes + 255) & ~size_t(255);
        return p;
    };
    float* hA     = (float*)alloc((size_t)N_ATOMS * D * 4);
    float* aggG   = (float*)alloc((size_t)N_ATOMS * D * 4);
    float* WT2    = (float*)alloc((size_t)D * QW * 4);
    int*   deg    = (int*)alloc((size_t)N_ATOMS * 4);
    int*   offs   = (int*)alloc((size_t)N_ATOMS * 4);
    int*   cursor = (int*)alloc((size_t)N_ATOMS * 4);
    int*   bsums  = (int*)alloc(256 * 4);
    int*   boffs  = (int*)alloc(256 * 4);
    int2*  sedge  = (int2*)alloc((size_t)E_EDGES * 8);

    hipMemsetAsync(deg, 0, (size_t)N_ATOMS * 4, stream);
    hipMemsetAsync(cursor, 0, (size_t)N_ATOMS * 4, stream);

    k_build_wt<<<(D * QW + 255) / 256, 256, 0, stream>>>(kern, bias, WT2);
    k_hist<<<(E_EDGES + 255) / 256, 256, 0, stream>>>(pair, deg);
    k_scan1<<<SCAN_BLOCKS, 256, 0, stream>>>(deg, offs, bsums);
    k_scan2<<<1, 256, 0, stream>>>(bsums, boffs, SCAN_BLOCKS);
    k_scan3<<<SCAN_BLOCKS, 256, 0, stream>>>(offs, boffs);
    k_scatter<<<(E_EDGES + 255) / 256, 256, 0, stream>>>(pair, offs, cursor, sedge);

    const float* hsrc = atom;
    float* hdst[4] = { hA, out, hA, out };
    for (int s = 0; s < 4; ++s) {
        k_msg<<<NTILES, 256, 0, stream>>>(hsrc, aggG, bond, WT2, offs, deg, sedge);
        k_gru<<<1024, 256, 0, stream>>>(aggG, hsrc, hdst[s], Wih, Whh, bih, bhh);
        hsrc = hdst[s];
    }
}

// Round 6
// 1520.363 us; speedup vs baseline: 1.0332x; 1.0332x over previous
//
#include <hip/hip_runtime.h>
#include <math.h>

#define N_ATOMS 50000
#define D 32
#define E_EDGES 300000
#define BD 16
#define NCH 17              // BD + 1 bias channel
#define QW (NCH * D)        // 544
#define TILE 16
#define NTILES (N_ATOMS / TILE)               // 3125 exact
#define SCAN_BLOCKS ((N_ATOMS + 255) / 256)   // 196
#define GRU_TILE 8
#define GRU_NT (N_ATOMS / GRU_TILE)           // 6250
#define EB 160                                // staged edges per batch (tile avg 96)

__device__ __forceinline__ float sigmoidf_(float x) {
    return 1.0f / (1.0f + __expf(-x));
}
__device__ __forceinline__ float dot4_(float4 a, float4 b, float acc) {
    return fmaf(a.x, b.x, fmaf(a.y, b.y, fmaf(a.z, b.z, fmaf(a.w, b.w, acc))));
}

// ---------- precompute kernels (once per launch) ----------

// WT2[i][s], i-major, s = b*32 + j ; channel b=16 is Bm (bias.reshape(D,D))
__global__ void k_build_wt(const float* __restrict__ kern,
                           const float* __restrict__ bias,
                           float* __restrict__ WT2) {
    int idx = blockIdx.x * 256 + threadIdx.x;
    if (idx >= D * QW) return;
    int i = idx / QW;
    int s = idx - i * QW;
    int b = s >> 5, j = s & 31;
    WT2[idx] = (b < BD) ? kern[b * (D * D) + i * D + j] : bias[i * D + j];
}

__global__ void k_hist(const int* __restrict__ pair, int* __restrict__ deg) {
    int e = blockIdx.x * 256 + threadIdx.x;
    if (e < E_EDGES) atomicAdd(&deg[pair[2 * e]], 1);
}

__global__ void k_scan1(const int* __restrict__ deg, int* __restrict__ offs,
                        int* __restrict__ bsums) {
    __shared__ int sm[256];
    int t = threadIdx.x, gid = blockIdx.x * 256 + t;
    int v = (gid < N_ATOMS) ? deg[gid] : 0;
    sm[t] = v;
    __syncthreads();
    for (int off = 1; off < 256; off <<= 1) {
        int x = (t >= off) ? sm[t - off] : 0;
        __syncthreads();
        sm[t] += x;
        __syncthreads();
    }
    if (gid < N_ATOMS) offs[gid] = sm[t] - v;
    if (t == 255) bsums[blockIdx.x] = sm[255];
}

__global__ void k_scan2(const int* __restrict__ bsums, int* __restrict__ boffs, int nb) {
    __shared__ int sm[256];
    int t = threadIdx.x;
    int v = (t < nb) ? bsums[t] : 0;
    sm[t] = v;
    __syncthreads();
    for (int off = 1; off < 256; off <<= 1) {
        int x = (t >= off) ? sm[t - off] : 0;
        __syncthreads();
        sm[t] += x;
        __syncthreads();
    }
    if (t < nb) boffs[t] = sm[t] - v;
}

__global__ void k_scan3(int* __restrict__ offs, const int* __restrict__ boffs) {
    int gid = blockIdx.x * 256 + threadIdx.x;
    if (gid < N_ATOMS) offs[gid] += boffs[blockIdx.x];
}

// sedge = (src, eid), CSR-sorted by dst
__global__ void k_scatter(const int* __restrict__ pair, const int* __restrict__ offs,
                          int* __restrict__ cursor, int2* __restrict__ sedge) {
    int e = blockIdx.x * 256 + threadIdx.x;
    if (e >= E_EDGES) return;
    int d = pair[2 * e], s = pair[2 * e + 1];
    int pos = offs[d] + atomicAdd(&cursor[d], 1);
    sedge[pos] = make_int2(s, e);
}

#define ACC17(QQ) do {                          \
    QQ[0]  = fmaf(b0.x, hv, QQ[0]);             \
    QQ[1]  = fmaf(b0.y, hv, QQ[1]);             \
    QQ[2]  = fmaf(b0.z, hv, QQ[2]);             \
    QQ[3]  = fmaf(b0.w, hv, QQ[3]);             \
    QQ[4]  = fmaf(b1.x, hv, QQ[4]);             \
    QQ[5]  = fmaf(b1.y, hv, QQ[5]);             \
    QQ[6]  = fmaf(b1.z, hv, QQ[6]);             \
    QQ[7]  = fmaf(b1.w, hv, QQ[7]);             \
    QQ[8]  = fmaf(b2.x, hv, QQ[8]);             \
    QQ[9]  = fmaf(b2.y, hv, QQ[9]);             \
    QQ[10] = fmaf(b2.z, hv, QQ[10]);            \
    QQ[11] = fmaf(b2.w, hv, QQ[11]);            \
    QQ[12] = fmaf(b3.x, hv, QQ[12]);            \
    QQ[13] = fmaf(b3.y, hv, QQ[13]);            \
    QQ[14] = fmaf(b3.z, hv, QQ[14]);            \
    QQ[15] = fmaf(b3.w, hv, QQ[15]);            \
    QQ[16] += hv;                               \
} while (0)

// ---------- message kernel: phases 1+2, writes agg to global ----------
// (256,2): r5 evidence — unlocks >64 VGPR with zero scratch (96 VGPR, WRITE
// collapsed to algorithmic 6.25 MB). Keep.
__global__ __launch_bounds__(256, 2)
void k_msg(const float* __restrict__ h_in, float* __restrict__ agg_g,
           const float* __restrict__ bond, const float* __restrict__ WT2,
           const int* __restrict__ offs, const int* __restrict__ deg,
           const int2* __restrict__ sedge) {
    __shared__ float q_lds[TILE][QW];     // 34816 B, bank(s) = s&31
    __shared__ float bond_s[EB][BD];      // 10240 B
    __shared__ float agg_lds[TILE][33];   //  2112 B   -> total 47168 B, 3 blk/CU

    const int t = threadIdx.x;
    const int base = blockIdx.x * TILE;
    const int half = t >> 5;   // 0..7
    const int j = t & 31;

    // ---- zero q_lds (float4) / agg_lds
    {
        const float4 z4 = make_float4(0.f, 0.f, 0.f, 0.f);
        float4* qz = (float4*)q_lds;      // 2176 float4
#pragma unroll
        for (int k = 0; k < 8; ++k) qz[t + 256 * k] = z4;
        if (t < 128) qz[2048 + t] = z4;
        const int r = t >> 5;
        agg_lds[r][j]     = 0.f;
        agg_lds[r + 8][j] = 0.f;
    }

    // ---- my 2 nodes (contiguous CSR windows)
    const int n0 = base + (half << 1);
    const int nst0 = offs[n0];
    const int m_glob = nst0 + deg[n0];          // boundary n0|n1
    const int nend_g = m_glob + deg[n0 + 1];

    const int estart = offs[base];
    const int lastn = base + TILE - 1;
    const int eend = offs[lastn] + deg[lastn];

    for (int ebase = estart; ebase < eend; ebase += EB) {
        const int ecnt = min(EB, eend - ebase);
        const int nch = ecnt * 4;   // 16B chunks to stage

        // ---- stage bond rows -> LDS (independent wide loads, high MLP)
        float4 breg[3];
        int cc[3];
#pragma unroll
        for (int it = 0; it < 3; ++it) {
            const int c = t + it * 256;
            cc[it] = c;
            if (c < nch) {
                const int eid = ((const int*)sedge)[(ebase + (c >> 2)) * 2 + 1];
                breg[it] = *(const float4*)(bond + (size_t)eid * BD + (c & 3) * 4);
            }
        }
        __syncthreads();   // prev-batch bond_s readers done (also covers q zeroing)
#pragma unroll
        for (int it = 0; it < 3; ++it)
            if (cc[it] < nch) ((float4*)bond_s)[cc[it]] = breg[it];
        __syncthreads();   // staging visible

        // ---- phase 1: my union window ∩ this batch, batch-8 hoisted gathers
        const int s = max(nst0, ebase);
        const int e = min(nend_g, ebase + ecnt);
        if (s < e) {
            float qA[NCH], qB[NCH];
#pragma unroll
            for (int k = 0; k < NCH; ++k) { qA[k] = 0.f; qB[k] = 0.f; }

            for (int p = s; p < e; p += 8) {
                const int cnt = min(8, e - p);
                int srcv[8];
                float hreg[8];
#pragma unroll
                for (int k = 0; k < 8; ++k) {
                    const int pp = min(p + k, e - 1);
                    srcv[k] = ((const int*)sedge)[2 * pp];
                }
#pragma unroll
                for (int k = 0; k < 8; ++k)
                    hreg[k] = h_in[(size_t)srcv[k] * D + j];   // 8 gathers in flight
#pragma unroll
                for (int k = 0; k < 8; ++k) {
                    if (k < cnt) {
                        const int pl = p + k - ebase;
                        const float* br = &bond_s[pl][0];
                        const float4 b0 = *(const float4*)(br);
                        const float4 b1 = *(const float4*)(br + 4);
                        const float4 b2 = *(const float4*)(br + 8);
                        const float4 b3 = *(const float4*)(br + 12);
                        const float hv = hreg[k];
                        if (p + k < m_glob) { ACC17(qA); }
                        else                { ACC17(qB); }
                    }
                }
            }
            const int r0 = half << 1;
#pragma unroll
            for (int k = 0; k < NCH; ++k)
                atomicAdd(&q_lds[r0][k * 32 + j], qA[k]);
#pragma unroll
            for (int k = 0; k < NCH; ++k)
                atomicAdd(&q_lds[r0 + 1][k * 32 + j], qB[k]);
        }
    }
    __syncthreads();

    // ---- phase 2: agg[r][j] += sum_{s in my 68-chunk} WT2[j][s] * q[r][s]
    {
        const int s0 = half * (QW / 8);   // 68-wide, 16B-aligned (272 B)
        const float4* wrow = (const float4*)(WT2 + (size_t)j * QW + s0);
#pragma unroll
        for (int pass = 0; pass < 2; ++pass) {
            const int rb = ((pass ^ (half & 1)) & 1) * 8;
            float acc[8];
#pragma unroll
            for (int r = 0; r < 8; ++r) acc[r] = 0.f;
            for (int sq = 0; sq < (QW / 8) / 4; ++sq) {    // 17 iters
                const float4 wv = wrow[sq];
#pragma unroll
                for (int r = 0; r < 8; ++r) {
                    const float4 qv = *(const float4*)&q_lds[rb + r][s0 + sq * 4];
                    acc[r] = dot4_(wv, qv, acc[r]);
                }
            }
#pragma unroll
            for (int r = 0; r < 8; ++r)
                atomicAdd(&agg_lds[rb + r][j], acc[r]);
        }
    }
    __syncthreads();

    // ---- epilogue: agg -> global (coalesced)
    {
        const int r = t >> 5;
        agg_g[base * D + t]       = agg_lds[r][j];
        agg_g[base * D + 256 + t] = agg_lds[r + 8][j];
    }
}

// ---------- GRU kernel: h_out = GRUCell(agg, h_in), next-tile prefetch ----------
__global__ __launch_bounds__(256, 2)
void k_gru(const float* __restrict__ agg_g, const float* __restrict__ h_in,
           float* __restrict__ h_out,
           const float* __restrict__ Wih, const float* __restrict__ Whh,
           const float* __restrict__ bih, const float* __restrict__ bhh) {
    __shared__ float Wih_s[96][33];       // 12672 B
    __shared__ float Whh_s[96][33];       // 12672 B
    __shared__ float bih_s[96], bhh_s[96];
    __shared__ float x_lds[GRU_TILE][32];
    __shared__ float h_lds[GRU_TILE][32];

    const int t = threadIdx.x;

    for (int idx = t; idx < 96 * 32; idx += 256) {
        const int o = idx >> 5, jj = idx & 31;
        Wih_s[o][jj] = Wih[idx];
        Whh_s[o][jj] = Whh[idx];
    }
    if (t < 96) { bih_s[t] = bih[t]; bhh_s[t] = bhh[t]; }

    const int r = t >> 5;   // node within octet
    const int i = t & 31;   // output feature
    const int stride = gridDim.x;

    int tile = blockIdx.x;
    float xr = 0.f, hr = 0.f;
    if (tile < GRU_NT) {
        xr = agg_g[tile * 256 + t];
        hr = h_in[tile * 256 + t];
    }
    for (; tile < GRU_NT; tile += stride) {
        ((float*)x_lds)[t] = xr;
        ((float*)h_lds)[t] = hr;
        __syncthreads();
        const int nxt = tile + stride;
        if (nxt < GRU_NT) {            // prefetch next tile during compute
            xr = agg_g[nxt * 256 + t];
            hr = h_in[nxt * 256 + t];
        }
        float gri = bih_s[i],      grh = bhh_s[i];
        float gzi = bih_s[32 + i], gzh = bhh_s[32 + i];
        float gni = bih_s[64 + i], gnh = bhh_s[64 + i];
#pragma unroll 8
        for (int jj = 0; jj < 32; ++jj) {
            const float xv = x_lds[r][jj];
            const float hv = h_lds[r][jj];
            gri = fmaf(Wih_s[i][jj],      xv, gri);
            gzi = fmaf(Wih_s[32 + i][jj], xv, gzi);
            gni = fmaf(Wih_s[64 + i][jj], xv, gni);
            grh = fmaf(Whh_s[i][jj],      hv, grh);
            gzh = fmaf(Whh_s[32 + i][jj], hv, gzh);
            gnh = fmaf(Whh_s[64 + i][jj], hv, gnh);
        }
        const float rg = sigmoidf_(gri + grh);
        const float zg = sigmoidf_(gzi + gzh);
        float xn = gni + rg * gnh;
        xn = fminf(fmaxf(xn, -15.f), 15.f);
        const float e2 = __expf(2.f * xn);
        const float ng = (e2 - 1.f) / (e2 + 1.f);
        h_out[tile * 256 + t] = (1.f - zg) * ng + zg * h_lds[r][i];
        __syncthreads();
    }
}

// ---------- launch ----------
extern "C" void kernel_launch(void* const* d_in, const int* in_sizes, int n_in,
                              void* d_out, int out_size, void* d_ws, size_t ws_size,
                              hipStream_t stream) {
    const float* atom = (const float*)d_in[0];
    const float* bond = (const float*)d_in[1];
    const int*   pair = (const int*)d_in[2];
    const float* kern = (const float*)d_in[3];
    const float* bias = (const float*)d_in[4];
    const float* Wih  = (const float*)d_in[5];
    const float* Whh  = (const float*)d_in[6];
    const float* bih  = (const float*)d_in[7];
    const float* bhh  = (const float*)d_in[8];
    float* out = (float*)d_out;

    char* w = (char*)d_ws;
    auto alloc = [&](size_t bytes) {
        char* p = w;
        w += (bytes + 255) & ~size_t(255);
        return p;
    };
    float* hA     = (float*)alloc((size_t)N_ATOMS * D * 4);
    float* aggG   = (float*)alloc((size_t)N_ATOMS * D * 4);
    float* WT2    = (float*)alloc((size_t)D * QW * 4);
    int*   deg    = (int*)alloc((size_t)N_ATOMS * 4);
    int*   offs   = (int*)alloc((size_t)N_ATOMS * 4);
    int*   cursor = (int*)alloc((size_t)N_ATOMS * 4);
    int*   bsums  = (int*)alloc(256 * 4);
    int*   boffs  = (int*)alloc(256 * 4);
    int2*  sedge  = (int2*)alloc((size_t)(E_EDGES + 8) * 8);

    hipMemsetAsync(deg, 0, (size_t)N_ATOMS * 4, stream);
    hipMemsetAsync(cursor, 0, (size_t)N_ATOMS * 4, stream);

    k_build_wt<<<(D * QW + 255) / 256, 256, 0, stream>>>(kern, bias, WT2);
    k_hist<<<(E_EDGES + 255) / 256, 256, 0, stream>>>(pair, deg);
    k_scan1<<<SCAN_BLOCKS, 256, 0, stream>>>(deg, offs, bsums);
    k_scan2<<<1, 256, 0, stream>>>(bsums, boffs, SCAN_BLOCKS);
    k_scan3<<<SCAN_BLOCKS, 256, 0, stream>>>(offs, boffs);
    k_scatter<<<(E_EDGES + 255) / 256, 256, 0, stream>>>(pair, offs, cursor, sedge);

    const float* hsrc = atom;
    float* hdst[4] = { hA, out, hA, out };
    for (int s = 0; s < 4; ++s) {
        k_msg<<<NTILES, 256, 0, stream>>>(hsrc, aggG, bond, WT2, offs, deg, sedge);
        k_gru<<<2048, 256, 0, stream>>>(aggG, hsrc, hdst[s], Wih, Whh, bih, bhh);
        hsrc = hdst[s];
    }
}

// Round 7
// 1031.049 us; speedup vs baseline: 1.5236x; 1.4746x over previous
//
#include <hip/hip_runtime.h>
#include <math.h>

#define N_ATOMS 50000
#define D 32
#define E_EDGES 300000
#define BD 16
#define SW 544                       // 17*32 extended channels (16 bond + 1 bias)
#define GRU_TILE 8
#define GRU_NT (N_ATOMS / GRU_TILE)  // 6250

// k_proj decomposition: 9 windows of 64 s-values (window 8 half-valid)
#define PJ_WIN 9
#define PJ_MB 228                    // m-slices; grid = 9*228 = 2052 blocks
#define EC 4                         // edges per half-wave in k_edge
#define EDGE_BLOCKS (E_EDGES / (8 * EC))   // 9375 exact

__device__ __forceinline__ float sigmoidf_(float x) {
    return 1.0f / (1.0f + __expf(-x));
}
__device__ __forceinline__ float dot4_(float4 a, float4 b, float acc) {
    return fmaf(a.x, b.x, fmaf(a.y, b.y, fmaf(a.z, b.z, fmaf(a.w, b.w, acc))));
}

// ---------- projection: Y[m, s] = sum_j Wext[s, j] * h[m, j] ----------
// Wext rows live in 32 VGPRs per lane for the whole kernel; h rows are
// wave-uniform loads (scalar path); no LDS, no barriers.
// Wext[s=b*32+i][j] = kernel[b*1024 + i*32 + j] = kernel[s*32+j] for s<512,
//                     bias[(s-512)*32 + j]      for s>=512   (identity map!)
__global__ __launch_bounds__(256, 2)
void k_proj(const float* __restrict__ h_in, float* __restrict__ Y,
            const float* __restrict__ kern, const float* __restrict__ bias) {
    const int lane = threadIdx.x & 63;
    const int wv   = threadIdx.x >> 6;          // 0..3
    const int win  = blockIdx.x % PJ_WIN;
    const int mblk = blockIdx.x / PJ_WIN;       // 0..PJ_MB-1
    const int s    = win * 64 + lane;
    const bool valid = (s < SW);

    float4 w4[8];
    {
        const float* wsrc = (s < 512) ? (kern + (size_t)s * 32)
                                      : (bias + (size_t)(s - 512) * 32);
#pragma unroll
        for (int k = 0; k < 8; ++k)
            w4[k] = valid ? ((const float4*)wsrc)[k]
                          : make_float4(0.f, 0.f, 0.f, 0.f);
    }

    const int stride = PJ_MB * 4;
    for (int m = mblk * 4 + wv; m < N_ATOMS; m += stride) {
        const float4* hp = (const float4*)(h_in + (size_t)m * D);   // uniform
        float acc = 0.f;
#pragma unroll
        for (int k = 0; k < 8; ++k)
            acc = dot4_(w4[k], hp[k], acc);
        if (valid) Y[(size_t)m * SW + s] = acc;
    }
}

// ---------- edge kernel: agg[dst] += sum_b bond_ext[e,b] * Y[src, b*32+i] ----------
// Edge-parallel, natural order (no sorting needed). Half-wave per edge,
// 2 edges interleaved for MLP (34 independent gathers in flight). No LDS,
// no barriers; aggregation via global fp32 atomics on the 6.4 MB agg
// (L2-resident, ~6 contenders per row).
__global__ __launch_bounds__(256, 2)
void k_edge(const float* __restrict__ Y, const float* __restrict__ bond,
            const int* __restrict__ pair, float* __restrict__ agg) {
    const int i  = threadIdx.x & 31;
    const int hw = threadIdx.x >> 5;            // 0..7
    const int p0 = (blockIdx.x * 8 + hw) * EC;

#pragma unroll
    for (int u = 0; u < EC; u += 2) {
        const int e0 = p0 + u;
        // pair rows (e0,e1) as one 16B uniform load: (d0,s0,d1,s1)
        const int4 pr = *(const int4*)(pair + 2 * e0);
        const float* y0p = Y + (size_t)pr.y * SW + i;
        const float* y1p = Y + (size_t)pr.w * SW + i;
        float y0[17], y1[17];
#pragma unroll
        for (int b = 0; b < 17; ++b) y0[b] = y0p[b * 32];
#pragma unroll
        for (int b = 0; b < 17; ++b) y1[b] = y1p[b * 32];

        const float4* b0p = (const float4*)(bond + (size_t)e0 * BD);
        const float4* b1p = (const float4*)(bond + (size_t)(e0 + 1) * BD);
        float a0 = y0[16];   // bias channel, bond == 1
        float a1 = y1[16];
#pragma unroll
        for (int g = 0; g < 4; ++g) {
            const float4 b0 = b0p[g];
            a0 = fmaf(b0.x, y0[4 * g + 0], a0);
            a0 = fmaf(b0.y, y0[4 * g + 1], a0);
            a0 = fmaf(b0.z, y0[4 * g + 2], a0);
            a0 = fmaf(b0.w, y0[4 * g + 3], a0);
            const float4 b1 = b1p[g];
            a1 = fmaf(b1.x, y1[4 * g + 0], a1);
            a1 = fmaf(b1.y, y1[4 * g + 1], a1);
            a1 = fmaf(b1.z, y1[4 * g + 2], a1);
            a1 = fmaf(b1.w, y1[4 * g + 3], a1);
        }
        atomicAdd(&agg[(size_t)pr.x * D + i], a0);
        atomicAdd(&agg[(size_t)pr.z * D + i], a1);
    }
}

// ---------- GRU kernel: h_out = GRUCell(agg, h_in), next-tile prefetch ----------
__global__ __launch_bounds__(256, 2)
void k_gru(const float* __restrict__ agg_g, const float* __restrict__ h_in,
           float* __restrict__ h_out,
           const float* __restrict__ Wih, const float* __restrict__ Whh,
           const float* __restrict__ bih, const float* __restrict__ bhh) {
    __shared__ float Wih_s[96][33];       // 12672 B
    __shared__ float Whh_s[96][33];       // 12672 B
    __shared__ float bih_s[96], bhh_s[96];
    __shared__ float x_lds[GRU_TILE][32];
    __shared__ float h_lds[GRU_TILE][32];

    const int t = threadIdx.x;

    for (int idx = t; idx < 96 * 32; idx += 256) {
        const int o = idx >> 5, jj = idx & 31;
        Wih_s[o][jj] = Wih[idx];
        Whh_s[o][jj] = Whh[idx];
    }
    if (t < 96) { bih_s[t] = bih[t]; bhh_s[t] = bhh[t]; }

    const int r = t >> 5;   // node within octet
    const int i = t & 31;   // output feature
    const int stride = gridDim.x;

    int tile = blockIdx.x;
    float xr = 0.f, hr = 0.f;
    if (tile < GRU_NT) {
        xr = agg_g[tile * 256 + t];
        hr = h_in[tile * 256 + t];
    }
    for (; tile < GRU_NT; tile += stride) {
        ((float*)x_lds)[t] = xr;
        ((float*)h_lds)[t] = hr;
        __syncthreads();
        const int nxt = tile + stride;
        if (nxt < GRU_NT) {            // prefetch next tile during compute
            xr = agg_g[nxt * 256 + t];
            hr = h_in[nxt * 256 + t];
        }
        float gri = bih_s[i],      grh = bhh_s[i];
        float gzi = bih_s[32 + i], gzh = bhh_s[32 + i];
        float gni = bih_s[64 + i], gnh = bhh_s[64 + i];
#pragma unroll 8
        for (int jj = 0; jj < 32; ++jj) {
            const float xv = x_lds[r][jj];
            const float hv = h_lds[r][jj];
            gri = fmaf(Wih_s[i][jj],      xv, gri);
            gzi = fmaf(Wih_s[32 + i][jj], xv, gzi);
            gni = fmaf(Wih_s[64 + i][jj], xv, gni);
            grh = fmaf(Whh_s[i][jj],      hv, grh);
            gzh = fmaf(Whh_s[32 + i][jj], hv, gzh);
            gnh = fmaf(Whh_s[64 + i][jj], hv, gnh);
        }
        const float rg = sigmoidf_(gri + grh);
        const float zg = sigmoidf_(gzi + gzh);
        float xn = gni + rg * gnh;
        xn = fminf(fmaxf(xn, -15.f), 15.f);
        const float e2 = __expf(2.f * xn);
        const float ng = (e2 - 1.f) / (e2 + 1.f);
        h_out[tile * 256 + t] = (1.f - zg) * ng + zg * h_lds[r][i];
        __syncthreads();
    }
}

// ---------- launch ----------
extern "C" void kernel_launch(void* const* d_in, const int* in_sizes, int n_in,
                              void* d_out, int out_size, void* d_ws, size_t ws_size,
                              hipStream_t stream) {
    const float* atom = (const float*)d_in[0];
    const float* bond = (const float*)d_in[1];
    const int*   pair = (const int*)d_in[2];
    const float* kern = (const float*)d_in[3];
    const float* bias = (const float*)d_in[4];
    const float* Wih  = (const float*)d_in[5];
    const float* Whh  = (const float*)d_in[6];
    const float* bih  = (const float*)d_in[7];
    const float* bhh  = (const float*)d_in[8];
    float* out = (float*)d_out;

    char* w = (char*)d_ws;
    auto alloc = [&](size_t bytes) {
        char* p = w;
        w += (bytes + 255) & ~size_t(255);
        return p;
    };
    float* hA   = (float*)alloc((size_t)N_ATOMS * D * 4);     //   6.4 MB
    float* aggG = (float*)alloc((size_t)N_ATOMS * D * 4);     //   6.4 MB
    float* Y    = (float*)alloc((size_t)N_ATOMS * SW * 4);    // 108.8 MB

    const float* hsrc = atom;
    float* hdst[4] = { hA, out, hA, out };
    for (int s = 0; s < 4; ++s) {
        hipMemsetAsync(aggG, 0, (size_t)N_ATOMS * D * 4, stream);
        k_proj<<<PJ_WIN * PJ_MB, 256, 0, stream>>>(hsrc, Y, kern, bias);
        k_edge<<<EDGE_BLOCKS, 256, 0, stream>>>(Y, bond, pair, aggG);
        k_gru<<<2048, 256, 0, stream>>>(aggG, hsrc, hdst[s], Wih, Whh, bih, bhh);
        hsrc = hdst[s];
    }
}

// Round 8
// 514.357 us; speedup vs baseline: 3.0541x; 2.0045x over previous
//
#include <hip/hip_runtime.h>
#include <math.h>

#define N_ATOMS 50000
#define D 32
#define E_EDGES 300000
#define BD 16
#define SW 544                                // 17*32 (16 bond ch + 1 bias ch)
#define SCAN_BLOCKS ((N_ATOMS + 255) / 256)   // 196
#define GRU_TILE 8
#define GRU_NT (N_ATOMS / GRU_TILE)           // 6250

#define NB 64                                 // src nodes per block (8 per half-wave)
#define FBLOCKS ((N_ATOMS + NB - 1) / NB)     // 782
#define EBF 512                               // staged edges per batch (block avg 384)

__device__ __forceinline__ float sigmoidf_(float x) {
    return 1.0f / (1.0f + __expf(-x));
}

// ---------- precompute (once per launch) ----------

// WTj[j*544 + b*32 + i] = W[b,i,j]  (b<16: kernel.reshape(16,32,32); b=16: Bm)
__global__ void k_build_wt(const float* __restrict__ kern,
                           const float* __restrict__ bias,
                           float* __restrict__ WTj) {
    int idx = blockIdx.x * 256 + threadIdx.x;
    if (idx >= 32 * SW) return;
    int j = idx / SW;
    int r = idx - j * SW;
    int b = r >> 5, i = r & 31;
    WTj[idx] = (b < BD) ? kern[b * 1024 + i * 32 + j] : bias[i * 32 + j];
}

// CSR by SRC (pair[:,1])
__global__ void k_hist(const int* __restrict__ pair, int* __restrict__ deg) {
    int e = blockIdx.x * 256 + threadIdx.x;
    if (e < E_EDGES) atomicAdd(&deg[pair[2 * e + 1]], 1);
}

__global__ void k_scan1(const int* __restrict__ deg, int* __restrict__ offs,
                        int* __restrict__ bsums) {
    __shared__ int sm[256];
    int t = threadIdx.x, gid = blockIdx.x * 256 + t;
    int v = (gid < N_ATOMS) ? deg[gid] : 0;
    sm[t] = v;
    __syncthreads();
    for (int off = 1; off < 256; off <<= 1) {
        int x = (t >= off) ? sm[t - off] : 0;
        __syncthreads();
        sm[t] += x;
        __syncthreads();
    }
    if (gid < N_ATOMS) offs[gid] = sm[t] - v;
    if (t == 255) bsums[blockIdx.x] = sm[255];
}

__global__ void k_scan2(const int* __restrict__ bsums, int* __restrict__ boffs, int nb) {
    __shared__ int sm[256];
    int t = threadIdx.x;
    int v = (t < nb) ? bsums[t] : 0;
    sm[t] = v;
    __syncthreads();
    for (int off = 1; off < 256; off <<= 1) {
        int x = (t >= off) ? sm[t - off] : 0;
        __syncthreads();
        sm[t] += x;
        __syncthreads();
    }
    if (t < nb) boffs[t] = sm[t] - v;
}

__global__ void k_scan3(int* __restrict__ offs, const int* __restrict__ boffs) {
    int gid = blockIdx.x * 256 + threadIdx.x;
    if (gid < N_ATOMS) offs[gid] += boffs[blockIdx.x];
}

// sedge[pos] = (dst, eid), sorted by src
__global__ void k_scatter(const int* __restrict__ pair, const int* __restrict__ offs,
                          int* __restrict__ cursor, int2* __restrict__ sedge) {
    int e = blockIdx.x * 256 + threadIdx.x;
    if (e >= E_EDGES) return;
    int d = pair[2 * e], s = pair[2 * e + 1];
    int pos = offs[s] + atomicAdd(&cursor[s], 1);
    sedge[pos] = make_int2(d, e);
}

// ---------- fused projection + edge kernel ----------
// Per half-wave: 8 src nodes. Phase A computes y[n][b] = Y[node_n, b*32+i]
// in registers (lane = feature i). Phase B walks the nodes' outgoing edges
// (src-sorted CSR, bond/dst staged in LDS per 512-edge batch) and fires one
// 128B global atomicAdd into agg[dst] per edge. Y never touches memory.
__global__ __launch_bounds__(256, 2)
void k_fused(const float* __restrict__ h_in, float* __restrict__ agg,
             const float* __restrict__ bond, const float* __restrict__ WTj,
             const int* __restrict__ offs, const int* __restrict__ deg,
             const int2* __restrict__ sedge) {
    __shared__ float h_lds[NB][33];       //  8448 B
    __shared__ float bond_s[EBF][BD];     // 32768 B
    __shared__ int   dst_s[EBF];          //  2048 B  -> ~43.3 KB, 3 blk/CU

    const int t = threadIdx.x;
    const int bbase = blockIdx.x * NB;
    const int i = t & 31;                 // feature lane
    const int grp = t >> 5;               // half-wave 0..7
    const int nbase = bbase + grp * 8;
    const int hn0 = grp * 8;

    // ---- stage h tile (coalesced, guarded for ghost nodes)
#pragma unroll
    for (int k = 0; k < 8; ++k) {
        const int idx = t + 256 * k;      // 0..2047
        const int n = idx >> 5, j = idx & 31;
        const int node = bbase + n;
        h_lds[n][j] = (node < N_ATOMS) ? h_in[(size_t)node * D + j] : 0.f;
    }

    // ---- per-node CSR windows (static-indexed regs)
    int stv[8], env[8];
#pragma unroll
    for (int n = 0; n < 8; ++n) {
        const int node = nbase + n;
        const bool ok = (node < N_ATOMS);
        const int o = ok ? offs[node] : 0;
        stv[n] = o;
        env[n] = o + (ok ? deg[node] : 0);
    }
    __syncthreads();

    // ---- Phase A: y[n][b] = sum_j WTj[j][b*32+i] * h[node_n][j]
    float y[8][17];
#pragma unroll
    for (int n = 0; n < 8; ++n)
#pragma unroll
        for (int b = 0; b < 17; ++b) y[n][b] = 0.f;

    for (int j = 0; j < 32; ++j) {        // NOT unrolled: keeps VGPR low
        float wv[17];
#pragma unroll
        for (int b = 0; b < 17; ++b)
            wv[b] = WTj[j * SW + b * 32 + i];   // coalesced 128B, L2-resident
#pragma unroll
        for (int n = 0; n < 8; ++n) {
            const float hv = h_lds[hn0 + n][j]; // LDS broadcast
#pragma unroll
            for (int b = 0; b < 17; ++b)
                y[n][b] = fmaf(wv[b], hv, y[n][b]);
        }
    }

    // ---- Phase B: edge batches
    const int lastn = min(bbase + NB - 1, N_ATOMS - 1);
    const int bstart = offs[bbase];
    const int bend = offs[lastn] + deg[lastn];

    for (int ebase = bstart; ebase < bend; ebase += EBF) {
        const int ecnt = min(EBF, bend - ebase);
        const int nch = ecnt * 4;         // 16B chunks
        __syncthreads();                  // prev-batch consumers done
#pragma unroll
        for (int k2 = 0; k2 < 8; ++k2) {
            const int c = t + 256 * k2;
            if (c < nch) {
                const int2 se = sedge[ebase + (c >> 2)];
                if ((c & 3) == 0) dst_s[c >> 2] = se.x;
                ((float4*)bond_s)[c] =
                    *(const float4*)(bond + (size_t)se.y * BD + (c & 3) * 4);
            }
        }
        __syncthreads();
        const int elim = ebase + ecnt;
#pragma unroll
        for (int n = 0; n < 8; ++n) {     // static n -> y[n][*] stays in regs
            const int s = max(stv[n], ebase);
            const int e = min(env[n], elim);
            for (int p = s; p < e; ++p) {
                const int l = p - ebase;
                const float4 b0 = *(const float4*)&bond_s[l][0];
                const float4 b1 = *(const float4*)&bond_s[l][4];
                const float4 b2 = *(const float4*)&bond_s[l][8];
                const float4 b3 = *(const float4*)&bond_s[l][12];
                float m = y[n][16];       // bias channel (bond == 1)
                m = fmaf(b0.x, y[n][0],  m); m = fmaf(b0.y, y[n][1],  m);
                m = fmaf(b0.z, y[n][2],  m); m = fmaf(b0.w, y[n][3],  m);
                m = fmaf(b1.x, y[n][4],  m); m = fmaf(b1.y, y[n][5],  m);
                m = fmaf(b1.z, y[n][6],  m); m = fmaf(b1.w, y[n][7],  m);
                m = fmaf(b2.x, y[n][8],  m); m = fmaf(b2.y, y[n][9],  m);
                m = fmaf(b2.z, y[n][10], m); m = fmaf(b2.w, y[n][11], m);
                m = fmaf(b3.x, y[n][12], m); m = fmaf(b3.y, y[n][13], m);
                m = fmaf(b3.z, y[n][14], m); m = fmaf(b3.w, y[n][15], m);
                atomicAdd(&agg[(size_t)dst_s[l] * D + i], m);
            }
        }
    }
}

// ---------- GRU kernel: h_out = GRUCell(agg, h_in), next-tile prefetch ----------
__global__ __launch_bounds__(256, 2)
void k_gru(const float* __restrict__ agg_g, const float* __restrict__ h_in,
           float* __restrict__ h_out,
           const float* __restrict__ Wih, const float* __restrict__ Whh,
           const float* __restrict__ bih, const float* __restrict__ bhh) {
    __shared__ float Wih_s[96][33];
    __shared__ float Whh_s[96][33];
    __shared__ float bih_s[96], bhh_s[96];
    __shared__ float x_lds[GRU_TILE][32];
    __shared__ float h_lds[GRU_TILE][32];

    const int t = threadIdx.x;

    for (int idx = t; idx < 96 * 32; idx += 256) {
        const int o = idx >> 5, jj = idx & 31;
        Wih_s[o][jj] = Wih[idx];
        Whh_s[o][jj] = Whh[idx];
    }
    if (t < 96) { bih_s[t] = bih[t]; bhh_s[t] = bhh[t]; }

    const int r = t >> 5;
    const int i = t & 31;
    const int stride = gridDim.x;

    int tile = blockIdx.x;
    float xr = 0.f, hr = 0.f;
    if (tile < GRU_NT) {
        xr = agg_g[tile * 256 + t];
        hr = h_in[tile * 256 + t];
    }
    for (; tile < GRU_NT; tile += stride) {
        ((float*)x_lds)[t] = xr;
        ((float*)h_lds)[t] = hr;
        __syncthreads();
        const int nxt = tile + stride;
        if (nxt < GRU_NT) {
            xr = agg_g[nxt * 256 + t];
            hr = h_in[nxt * 256 + t];
        }
        float gri = bih_s[i],      grh = bhh_s[i];
        float gzi = bih_s[32 + i], gzh = bhh_s[32 + i];
        float gni = bih_s[64 + i], gnh = bhh_s[64 + i];
#pragma unroll 8
        for (int jj = 0; jj < 32; ++jj) {
            const float xv = x_lds[r][jj];
            const float hv = h_lds[r][jj];
            gri = fmaf(Wih_s[i][jj],      xv, gri);
            gzi = fmaf(Wih_s[32 + i][jj], xv, gzi);
            gni = fmaf(Wih_s[64 + i][jj], xv, gni);
            grh = fmaf(Whh_s[i][jj],      hv, grh);
            gzh = fmaf(Whh_s[32 + i][jj], hv, gzh);
            gnh = fmaf(Whh_s[64 + i][jj], hv, gnh);
        }
        const float rg = sigmoidf_(gri + grh);
        const float zg = sigmoidf_(gzi + gzh);
        float xn = gni + rg * gnh;
        xn = fminf(fmaxf(xn, -15.f), 15.f);
        const float e2 = __expf(2.f * xn);
        const float ng = (e2 - 1.f) / (e2 + 1.f);
        h_out[tile * 256 + t] = (1.f - zg) * ng + zg * h_lds[r][i];
        __syncthreads();
    }
}

// ---------- launch ----------
extern "C" void kernel_launch(void* const* d_in, const int* in_sizes, int n_in,
                              void* d_out, int out_size, void* d_ws, size_t ws_size,
                              hipStream_t stream) {
    const float* atom = (const float*)d_in[0];
    const float* bond = (const float*)d_in[1];
    const int*   pair = (const int*)d_in[2];
    const float* kern = (const float*)d_in[3];
    const float* bias = (const float*)d_in[4];
    const float* Wih  = (const float*)d_in[5];
    const float* Whh  = (const float*)d_in[6];
    const float* bih  = (const float*)d_in[7];
    const float* bhh  = (const float*)d_in[8];
    float* out = (float*)d_out;

    char* w = (char*)d_ws;
    auto alloc = [&](size_t bytes) {
        char* p = w;
        w += (bytes + 255) & ~size_t(255);
        return p;
    };
    float* hA     = (float*)alloc((size_t)N_ATOMS * D * 4);
    float* aggG   = (float*)alloc((size_t)N_ATOMS * D * 4);
    float* WTj    = (float*)alloc((size_t)32 * SW * 4);
    int*   deg    = (int*)alloc((size_t)N_ATOMS * 4);
    int*   offs   = (int*)alloc((size_t)N_ATOMS * 4);
    int*   cursor = (int*)alloc((size_t)N_ATOMS * 4);
    int*   bsums  = (int*)alloc(256 * 4);
    int*   boffs  = (int*)alloc(256 * 4);
    int2*  sedge  = (int2*)alloc((size_t)E_EDGES * 8);

    hipMemsetAsync(deg, 0, (size_t)N_ATOMS * 4, stream);
    hipMemsetAsync(cursor, 0, (size_t)N_ATOMS * 4, stream);

    k_build_wt<<<(32 * SW + 255) / 256, 256, 0, stream>>>(kern, bias, WTj);
    k_hist<<<(E_EDGES + 255) / 256, 256, 0, stream>>>(pair, deg);
    k_scan1<<<SCAN_BLOCKS, 256, 0, stream>>>(deg, offs, bsums);
    k_scan2<<<1, 256, 0, stream>>>(bsums, boffs, SCAN_BLOCKS);
    k_scan3<<<SCAN_BLOCKS, 256, 0, stream>>>(offs, boffs);
    k_scatter<<<(E_EDGES + 255) / 256, 256, 0, stream>>>(pair, offs, cursor, sedge);

    const float* hsrc = atom;
    float* hdst[4] = { hA, out, hA, out };
    for (int s = 0; s < 4; ++s) {
        hipMemsetAsync(aggG, 0, (size_t)N_ATOMS * D * 4, stream);
        k_fused<<<FBLOCKS, 256, 0, stream>>>(hsrc, aggG, bond, WTj, offs, deg, sedge);
        k_gru<<<2048, 256, 0, stream>>>(aggG, hsrc, hdst[s], Wih, Whh, bih, bhh);
        hsrc = hdst[s];
    }
}

// Round 9
// 496.822 us; speedup vs baseline: 3.1619x; 1.0353x over previous
//
#include <hip/hip_runtime.h>
#include <math.h>

#define N_ATOMS 50000
#define D 32
#define E_EDGES 300000
#define BD 16
#define SW 544                                // 17*32 (16 bond ch + 1 bias ch)
#define SCAN_BLOCKS ((N_ATOMS + 255) / 256)   // 196
#define GRU_TILE 8
#define GRU_NT (N_ATOMS / GRU_TILE)           // 6250

#define NB 32                                 // src nodes per block (4 per half-wave)
#define FBLOCKS ((N_ATOMS + NB - 1) / NB)     // 1563

__device__ __forceinline__ float sigmoidf_(float x) {
    return 1.0f / (1.0f + __expf(-x));
}

// ---------- precompute (once per launch) ----------

// WTj[j*544 + b*32 + i] = W[b,i,j]  (b<16: kernel.reshape(16,32,32); b=16: Bm)
__global__ void k_build_wt(const float* __restrict__ kern,
                           const float* __restrict__ bias,
                           float* __restrict__ WTj) {
    int idx = blockIdx.x * 256 + threadIdx.x;
    if (idx >= 32 * SW) return;
    int j = idx / SW;
    int r = idx - j * SW;
    int b = r >> 5, i = r & 31;
    WTj[idx] = (b < BD) ? kern[b * 1024 + i * 32 + j] : bias[i * 32 + j];
}

// CSR by SRC (pair[:,1])
__global__ void k_hist(const int* __restrict__ pair, int* __restrict__ deg) {
    int e = blockIdx.x * 256 + threadIdx.x;
    if (e < E_EDGES) atomicAdd(&deg[pair[2 * e + 1]], 1);
}

__global__ void k_scan1(const int* __restrict__ deg, int* __restrict__ offs,
                        int* __restrict__ bsums) {
    __shared__ int sm[256];
    int t = threadIdx.x, gid = blockIdx.x * 256 + t;
    int v = (gid < N_ATOMS) ? deg[gid] : 0;
    sm[t] = v;
    __syncthreads();
    for (int off = 1; off < 256; off <<= 1) {
        int x = (t >= off) ? sm[t - off] : 0;
        __syncthreads();
        sm[t] += x;
        __syncthreads();
    }
    if (gid < N_ATOMS) offs[gid] = sm[t] - v;
    if (t == 255) bsums[blockIdx.x] = sm[255];
}

__global__ void k_scan2(const int* __restrict__ bsums, int* __restrict__ boffs, int nb) {
    __shared__ int sm[256];
    int t = threadIdx.x;
    int v = (t < nb) ? bsums[t] : 0;
    sm[t] = v;
    __syncthreads();
    for (int off = 1; off < 256; off <<= 1) {
        int x = (t >= off) ? sm[t - off] : 0;
        __syncthreads();
        sm[t] += x;
        __syncthreads();
    }
    if (t < nb) boffs[t] = sm[t] - v;
}

__global__ void k_scan3(int* __restrict__ offs, const int* __restrict__ boffs) {
    int gid = blockIdx.x * 256 + threadIdx.x;
    if (gid < N_ATOMS) offs[gid] += boffs[blockIdx.x];
}

// Permute edges to src-CSR order; materialize bond rows and dst in that order.
// bond_perm reused across all 4 steps -> Phase B reads become linear streams.
__global__ void k_scatter_perm(const int* __restrict__ pair, const int* __restrict__ offs,
                               int* __restrict__ cursor, const float* __restrict__ bond,
                               float* __restrict__ bond_perm, int* __restrict__ dst_perm) {
    int e = blockIdx.x * 256 + threadIdx.x;
    if (e >= E_EDGES) return;
    int d = pair[2 * e], s = pair[2 * e + 1];
    int pos = offs[s] + atomicAdd(&cursor[s], 1);
    dst_perm[pos] = d;
    const float4* src4 = (const float4*)(bond + (size_t)e * BD);
    float4* dst4 = (float4*)(bond_perm + (size_t)pos * BD);
    dst4[0] = src4[0];
    dst4[1] = src4[1];
    dst4[2] = src4[2];
    dst4[3] = src4[3];
}

#define EDGE_FMA(M, B0, B1, B2, B3, YN) do {            \
    M = fmaf(B0.x, YN[0],  M); M = fmaf(B0.y, YN[1],  M); \
    M = fmaf(B0.z, YN[2],  M); M = fmaf(B0.w, YN[3],  M); \
    M = fmaf(B1.x, YN[4],  M); M = fmaf(B1.y, YN[5],  M); \
    M = fmaf(B1.z, YN[6],  M); M = fmaf(B1.w, YN[7],  M); \
    M = fmaf(B2.x, YN[8],  M); M = fmaf(B2.y, YN[9],  M); \
    M = fmaf(B2.z, YN[10], M); M = fmaf(B2.w, YN[11], M); \
    M = fmaf(B3.x, YN[12], M); M = fmaf(B3.y, YN[13], M); \
    M = fmaf(B3.z, YN[14], M); M = fmaf(B3.w, YN[15], M); \
} while (0)

// ---------- fused projection + edge kernel ----------
// Per half-wave: 4 src nodes. Phase A: y[n][b] = sum_j Wext[b,i,j]*h[node,j]
// in registers (lane = feature i). Phase B: walk the nodes' outgoing edges in
// CSR order -- bond_perm/dst_perm are LINEAR streams (no staging, no barriers)
// -- and fire one 128B atomicAdd into agg[dst] per edge.
__global__ __launch_bounds__(256, 2)
void k_fused(const float* __restrict__ h_in, float* __restrict__ agg,
             const float* __restrict__ bond_perm, const int* __restrict__ dst_perm,
             const float* __restrict__ WTj,
             const int* __restrict__ offs, const int* __restrict__ deg) {
    __shared__ float h_lds[NB][33];       // 4224 B only

    const int t = threadIdx.x;
    const int bbase = blockIdx.x * NB;
    const int i = t & 31;                 // feature lane
    const int grp = t >> 5;               // half-wave 0..7
    const int hn0 = grp * 4;

    // ---- stage h tile (coalesced, guarded)
#pragma unroll
    for (int k = 0; k < 4; ++k) {
        const int idx = t + 256 * k;      // 0..1023
        const int n = idx >> 5, j = idx & 31;
        const int node = bbase + n;
        h_lds[n][j] = (node < N_ATOMS) ? h_in[(size_t)node * D + j] : 0.f;
    }

    // ---- per-node CSR windows (static regs)
    int stv[4], env[4];
#pragma unroll
    for (int n = 0; n < 4; ++n) {
        const int node = bbase + hn0 + n;
        const bool ok = (node < N_ATOMS);
        const int o = ok ? offs[node] : 0;
        stv[n] = o;
        env[n] = o + (ok ? deg[node] : 0);
    }
    __syncthreads();

    // ---- Phase A: y[n][b] = sum_j WTj[j][b*32+i] * h[node_n][j]
    float y[4][17];
#pragma unroll
    for (int n = 0; n < 4; ++n)
#pragma unroll
        for (int b = 0; b < 17; ++b) y[n][b] = 0.f;

    for (int j = 0; j < 32; ++j) {        // not unrolled: keeps VGPR low
        float wv[17];
#pragma unroll
        for (int b = 0; b < 17; ++b)
            wv[b] = WTj[j * SW + b * 32 + i];   // coalesced, L1/L2-resident
#pragma unroll
        for (int n = 0; n < 4; ++n) {
            const float hv = h_lds[hn0 + n][j]; // LDS broadcast
#pragma unroll
            for (int b = 0; b < 17; ++b)
                y[n][b] = fmaf(wv[b], hv, y[n][b]);
        }
    }

    // ---- Phase B: linear edge streams, unroll-2 for MLP, no barriers
#pragma unroll
    for (int n = 0; n < 4; ++n) {
        int p = stv[n];
        const int e = env[n];
        for (; p + 2 <= e; p += 2) {
            const float4* bp0 = (const float4*)(bond_perm + (size_t)p * BD);
            const float4* bp1 = (const float4*)(bond_perm + (size_t)(p + 1) * BD);
            const int d0 = dst_perm[p];
            const int d1 = dst_perm[p + 1];
            const float4 a0 = bp0[0], a1 = bp0[1], a2 = bp0[2], a3 = bp0[3];
            const float4 c0 = bp1[0], c1 = bp1[1], c2 = bp1[2], c3 = bp1[3];
            float m0 = y[n][16];          // bias channel (bond == 1)
            float m1 = y[n][16];
            EDGE_FMA(m0, a0, a1, a2, a3, y[n]);
            EDGE_FMA(m1, c0, c1, c2, c3, y[n]);
            atomicAdd(&agg[(size_t)d0 * D + i], m0);
            atomicAdd(&agg[(size_t)d1 * D + i], m1);
        }
        if (p < e) {
            const float4* bp0 = (const float4*)(bond_perm + (size_t)p * BD);
            const int d0 = dst_perm[p];
            const float4 a0 = bp0[0], a1 = bp0[1], a2 = bp0[2], a3 = bp0[3];
            float m0 = y[n][16];
            EDGE_FMA(m0, a0, a1, a2, a3, y[n]);
            atomicAdd(&agg[(size_t)d0 * D + i], m0);
        }
    }
}

// ---------- GRU kernel: h_out = GRUCell(agg, h_in); zeroes agg after read ----------
__global__ __launch_bounds__(256, 2)
void k_gru(float* __restrict__ agg_g, const float* __restrict__ h_in,
           float* __restrict__ h_out,
           const float* __restrict__ Wih, const float* __restrict__ Whh,
           const float* __restrict__ bih, const float* __restrict__ bhh) {
    __shared__ float Wih_s[96][33];
    __shared__ float Whh_s[96][33];
    __shared__ float bih_s[96], bhh_s[96];
    __shared__ float x_lds[GRU_TILE][32];
    __shared__ float h_lds[GRU_TILE][32];

    const int t = threadIdx.x;

    for (int idx = t; idx < 96 * 32; idx += 256) {
        const int o = idx >> 5, jj = idx & 31;
        Wih_s[o][jj] = Wih[idx];
        Whh_s[o][jj] = Whh[idx];
    }
    if (t < 96) { bih_s[t] = bih[t]; bhh_s[t] = bhh[t]; }

    const int r = t >> 5;
    const int i = t & 31;
    const int stride = gridDim.x;

    int tile = blockIdx.x;
    float xr = 0.f, hr = 0.f;
    if (tile < GRU_NT) {
        xr = agg_g[tile * 256 + t];
        hr = h_in[tile * 256 + t];
    }
    for (; tile < GRU_NT; tile += stride) {
        ((float*)x_lds)[t] = xr;
        ((float*)h_lds)[t] = hr;
        agg_g[tile * 256 + t] = 0.f;      // consumed -> zero for next step
        __syncthreads();
        const int nxt = tile + stride;
        if (nxt < GRU_NT) {               // prefetch next tile during compute
            xr = agg_g[nxt * 256 + t];
            hr = h_in[nxt * 256 + t];
        }
        float gri = bih_s[i],      grh = bhh_s[i];
        float gzi = bih_s[32 + i], gzh = bhh_s[32 + i];
        float gni = bih_s[64 + i], gnh = bhh_s[64 + i];
#pragma unroll 8
        for (int jj = 0; jj < 32; ++jj) {
            const float xv = x_lds[r][jj];
            const float hv = h_lds[r][jj];
            gri = fmaf(Wih_s[i][jj],      xv, gri);
            gzi = fmaf(Wih_s[32 + i][jj], xv, gzi);
            gni = fmaf(Wih_s[64 + i][jj], xv, gni);
            grh = fmaf(Whh_s[i][jj],      hv, grh);
            gzh = fmaf(Whh_s[32 + i][jj], hv, gzh);
            gnh = fmaf(Whh_s[64 + i][jj], hv, gnh);
        }
        const float rg = sigmoidf_(gri + grh);
        const float zg = sigmoidf_(gzi + gzh);
        float xn = gni + rg * gnh;
        xn = fminf(fmaxf(xn, -15.f), 15.f);
        const float e2 = __expf(2.f * xn);
        const float ng = (e2 - 1.f) / (e2 + 1.f);
        h_out[tile * 256 + t] = (1.f - zg) * ng + zg * h_lds[r][i];
        __syncthreads();
    }
}

// ---------- launch ----------
extern "C" void kernel_launch(void* const* d_in, const int* in_sizes, int n_in,
                              void* d_out, int out_size, void* d_ws, size_t ws_size,
                              hipStream_t stream) {
    const float* atom = (const float*)d_in[0];
    const float* bond = (const float*)d_in[1];
    const int*   pair = (const int*)d_in[2];
    const float* kern = (const float*)d_in[3];
    const float* bias = (const float*)d_in[4];
    const float* Wih  = (const float*)d_in[5];
    const float* Whh  = (const float*)d_in[6];
    const float* bih  = (const float*)d_in[7];
    const float* bhh  = (const float*)d_in[8];
    float* out = (float*)d_out;

    char* w = (char*)d_ws;
    auto alloc = [&](size_t bytes) {
        char* p = w;
        w += (bytes + 255) & ~size_t(255);
        return p;
    };
    float* hA        = (float*)alloc((size_t)N_ATOMS * D * 4);
    float* aggG      = (float*)alloc((size_t)N_ATOMS * D * 4);
    float* WTj       = (float*)alloc((size_t)32 * SW * 4);
    int*   deg       = (int*)alloc((size_t)N_ATOMS * 4);
    int*   offs      = (int*)alloc((size_t)N_ATOMS * 4);
    int*   cursor    = (int*)alloc((size_t)N_ATOMS * 4);
    int*   bsums     = (int*)alloc(256 * 4);
    int*   boffs     = (int*)alloc(256 * 4);
    int*   dst_perm  = (int*)alloc((size_t)E_EDGES * 4);
    float* bond_perm = (float*)alloc((size_t)E_EDGES * BD * 4);

    hipMemsetAsync(deg, 0, (size_t)N_ATOMS * 4, stream);
    hipMemsetAsync(cursor, 0, (size_t)N_ATOMS * 4, stream);
    hipMemsetAsync(aggG, 0, (size_t)N_ATOMS * D * 4, stream);  // thereafter k_gru re-zeroes

    k_build_wt<<<(32 * SW + 255) / 256, 256, 0, stream>>>(kern, bias, WTj);
    k_hist<<<(E_EDGES + 255) / 256, 256, 0, stream>>>(pair, deg);
    k_scan1<<<SCAN_BLOCKS, 256, 0, stream>>>(deg, offs, bsums);
    k_scan2<<<1, 256, 0, stream>>>(bsums, boffs, SCAN_BLOCKS);
    k_scan3<<<SCAN_BLOCKS, 256, 0, stream>>>(offs, boffs);
    k_scatter_perm<<<(E_EDGES + 255) / 256, 256, 0, stream>>>(pair, offs, cursor,
                                                              bond, bond_perm, dst_perm);

    const float* hsrc = atom;
    float* hdst[4] = { hA, out, hA, out };
    for (int s = 0; s < 4; ++s) {
        k_fused<<<FBLOCKS, 256, 0, stream>>>(hsrc, aggG, bond_perm, dst_perm,
                                             WTj, offs, deg);
        k_gru<<<2048, 256, 0, stream>>>(aggG, hsrc, hdst[s], Wih, Whh, bih, bhh);
        hsrc = hdst[s];
    }
}